// Round 1
// baseline (2602.450 us; speedup 1.0000x reference)
//
#include <hip/hip_runtime.h>
#include <hip/hip_bf16.h>

#define DD 128
#define LL 8
#define MM 32768
#define NN (LL*MM)
#define GG 5
#define FF 2
#define SORT_STRIDE 33408   // 32768 + 5*128 headroom

typedef __attribute__((ext_vector_type(8))) short short8;
typedef __attribute__((ext_vector_type(4))) float f32x4;

#define MFMA16(a,b,c) __builtin_amdgcn_mfma_f32_16x16x32_bf16((a),(b),(c),0,0,0)

__device__ __forceinline__ short f2bf(float x){
  __hip_bfloat16 h = __float2bfloat16(x);
  return *reinterpret_cast<short*>(&h);
}

__device__ __forceinline__ short8 pack8(float4 a, float4 b){
  short8 r;
  r[0]=f2bf(a.x); r[1]=f2bf(a.y); r[2]=f2bf(a.z); r[3]=f2bf(a.w);
  r[4]=f2bf(b.x); r[5]=f2bf(b.y); r[6]=f2bf(b.z); r[7]=f2bf(b.w);
  return r;
}

// Stage rows [kb,kb+32) of a row-major (*,128) f32 matrix into LDS transposed:
// wt[col*40 + k], k in [0,32). Stride 40 (+8 pad) -> 2-way (free) bank pattern
// on the b128 fragment reads.
__device__ __forceinline__ void stageW(const float* __restrict__ Wp, int kb, short* wt){
  const int t = threadIdx.x;
  const int cb = (t & 31) << 2;
  const int kr = t >> 5;
#pragma unroll
  for (int s2 = 0; s2 < 4; ++s2){
    const int k = kr + (s2 << 3);
    float4 v = *(const float4*)(Wp + (size_t)(kb + k)*DD + cb);
    wt[(cb+0)*40 + k] = f2bf(v.x);
    wt[(cb+1)*40 + k] = f2bf(v.y);
    wt[(cb+2)*40 + k] = f2bf(v.z);
    wt[(cb+3)*40 + k] = f2bf(v.w);
  }
}

// ---------------- bucket sort by gate, per level ----------------
__global__ void count_kernel(const int* __restrict__ gate, int* __restrict__ cnt){
  int idx = blockIdx.x*256 + threadIdx.x;      // 0 .. 7*32768-1
  int li = idx >> 15;
  int m  = idx & 32767;
  int g = gate[(li+1)*MM + m];
  atomicAdd(&cnt[li*GG + g], 1);
}

__global__ void offs_kernel(const int* __restrict__ cnt, int* __restrict__ off, int* __restrict__ pend){
  int l = threadIdx.x;
  if (l < LL-1){
    int o = 0;
    for (int g = 0; g < GG; ++g){
      off[l*GG+g] = o;
      int c = cnt[l*GG+g];
      pend[l*GG+g] = o + c;                 // valid region end
      o += ((c + 127) >> 7) << 7;           // pad each bucket to 128
    }
  }
}

__global__ void scatter_kernel(const int* __restrict__ gate, const int* __restrict__ off,
                               int* __restrict__ cur, int* __restrict__ sorted){
  int idx = blockIdx.x*256 + threadIdx.x;
  int li = idx >> 15;
  int m  = idx & 32767;
  int g = gate[(li+1)*MM + m];
  int p = atomicAdd(&cur[li*GG + g], 1);
  sorted[li*SORT_STRIDE + off[li*GG+g] + p] = m;
}

// ---------------- hs = [s|t] @ hs_W + hs_b ----------------
__global__ __launch_bounds__(256) void hs_kernel(
    const float* __restrict__ s, const float* __restrict__ t,
    const float* __restrict__ W, const float* __restrict__ b,
    float* __restrict__ hs)
{
  __shared__ __align__(16) short wt[128*40];
  __shared__ float bias[128];
  const int tid = threadIdx.x, lane = tid & 63, w = tid >> 6;
  const int l15 = lane & 15, lq = lane >> 4;
  if (tid < 128) bias[tid] = b[tid];
  const int row0 = blockIdx.x*256 + w*64;

  f32x4 zf = {0.f,0.f,0.f,0.f};
  f32x4 acc[4][8];
#pragma unroll
  for (int rt=0;rt<4;++rt)
#pragma unroll
    for (int nt=0;nt<8;++nt) acc[rt][nt] = zf;

  for (int kb = 0; kb < 2*DD; kb += 32){
    __syncthreads();
    stageW(W, kb, wt);
    __syncthreads();
    const float* base = (kb < DD) ? s : t;
    const int koff = kb & (DD-1);
    short8 afr[4];
#pragma unroll
    for (int rt=0;rt<4;++rt){
      int gr = row0 + rt*16 + l15;
      const float* p = base + (size_t)gr*DD + koff + (lq<<3);
      afr[rt] = pack8(*(const float4*)p, *(const float4*)(p+4));
    }
#pragma unroll
    for (int nt=0;nt<8;++nt){
      short8 bfr = *(const short8*)(wt + (nt*16 + l15)*40 + (lq<<3));
#pragma unroll
      for (int rt=0;rt<4;++rt)
        acc[rt][nt] = MFMA16(afr[rt], bfr, acc[rt][nt]);
    }
  }
#pragma unroll
  for (int rt=0;rt<4;++rt)
#pragma unroll
    for (int nt=0;nt<8;++nt){
      int col = nt*16 + l15;
      int r0 = row0 + rt*16 + (lq<<2);
      float bv = bias[col];
#pragma unroll
      for (int j=0;j<4;++j)
        hs[(size_t)(r0+j)*DD + col] = acc[rt][nt][j] + bv;
    }
}

// ---------------- fused per-level kernel ----------------
// Block: 64 nodes of one gate bucket (128 (node,fanin) rows).
// GEMM1 (256->128, gathered A) -> relu -> GEMM2 (128->128) -> relu ->
// GEMM3 (128->128) -> pair-sum over F -> msg -> GRU GEMM (128->3*128) ->
// sigmoid/tanh epilogue -> hf scatter.
__global__ __launch_bounds__(256) void level_kernel(
    int lvl, const float* __restrict__ hsg, float* __restrict__ hfg,
    const int* __restrict__ fanin,
    const float* __restrict__ W1, const float* __restrict__ b1,
    const float* __restrict__ W2, const float* __restrict__ b2,
    const float* __restrict__ W3, const float* __restrict__ b3,
    const float* __restrict__ Wi, const float* __restrict__ bi,
    const float* __restrict__ bh,
    const int* __restrict__ off, const int* __restrict__ pend,
    const int* __restrict__ sorted)
{
  __shared__ __align__(16) short hbuf[128*136];
  __shared__ __align__(16) short wstage[6528];   // max(128*40, 48*136)
  __shared__ float biasb[128*3 + 384*2];         // b1,b2,b3,bi,bh
  __shared__ int nodebuf[64];
  __shared__ int srcbuf[128];
  __shared__ int ginfo[1];

  const int tid = threadIdx.x;
  const int lane = tid & 63;
  const int w = tid >> 6;
  const int li = lvl - 1;
  const int pos0 = blockIdx.x * 64;
  const int l15 = lane & 15, lq = lane >> 4;

  if (tid == 0){
    int g = -1;
    for (int q = 0; q < GG; ++q)
      if (pos0 >= off[li*GG+q] && pos0 < pend[li*GG+q]) { g = q; break; }
    ginfo[0] = g;
  }
  __syncthreads();
  const int g = ginfo[0];
  if (g < 0) return;                 // uniform across block

  if (tid < 64) nodebuf[tid] = sorted[li*SORT_STRIDE + pos0 + tid];
  if (tid < 128){
    biasb[tid]     = b1[g*DD + tid];
    biasb[128+tid] = b2[g*DD + tid];
    biasb[256+tid] = b3[g*DD + tid];
  }
  for (int i = tid; i < 384; i += 256){
    biasb[384+i] = bi[g*384 + i];
    biasb[768+i] = bh[g*384 + i];
  }
  __syncthreads();
  if (tid < 128){
    int m = nodebuf[tid>>1];
    int sv = 0;
    if (m >= 0) sv = li*MM + fanin[((size_t)li*MM + m)*FF + (tid & 1)];
    srcbuf[tid] = sv;
  }

  f32x4 zf = {0.f,0.f,0.f,0.f};

  // ---- GEMM1: X(128x256) @ W1[g](256x128) ----
  f32x4 acc[2][8];
#pragma unroll
  for (int rt=0;rt<2;++rt)
#pragma unroll
    for (int nt=0;nt<8;++nt) acc[rt][nt] = zf;

  const float* W1g = W1 + (size_t)g*2*DD*DD;
  for (int kb = 0; kb < 2*DD; kb += 32){
    __syncthreads();
    stageW(W1g, kb, wstage);
    __syncthreads();
    const float* base = (kb < DD) ? hsg : hfg;
    const int koff = kb & (DD-1);
    short8 afr[2];
#pragma unroll
    for (int rt=0;rt<2;++rt){
      int r = w*32 + rt*16 + l15;
      int src = srcbuf[r];
      const float* p = base + (size_t)src*DD + koff + (lq<<3);
      afr[rt] = pack8(*(const float4*)p, *(const float4*)(p+4));
    }
#pragma unroll
    for (int nt=0;nt<8;++nt){
      short8 bfr = *(const short8*)(wstage + (nt*16 + l15)*40 + (lq<<3));
      acc[0][nt] = MFMA16(afr[0], bfr, acc[0][nt]);
      acc[1][nt] = MFMA16(afr[1], bfr, acc[1][nt]);
    }
  }
#pragma unroll
  for (int rt=0;rt<2;++rt)
#pragma unroll
    for (int nt=0;nt<8;++nt){
      int col = nt*16 + l15;
      int r0 = w*32 + rt*16 + (lq<<2);
      float bv = biasb[col];
#pragma unroll
      for (int j=0;j<4;++j)
        hbuf[(r0+j)*136 + col] = f2bf(fmaxf(acc[rt][nt][j] + bv, 0.f));
    }
  __syncthreads();

  // ---- GEMM2: H1(128x128) @ W2[g] ----
  f32x4 acc2[2][8];
#pragma unroll
  for (int rt=0;rt<2;++rt)
#pragma unroll
    for (int nt=0;nt<8;++nt) acc2[rt][nt] = zf;

  const float* W2g = W2 + (size_t)g*DD*DD;
  for (int kb = 0; kb < DD; kb += 32){
    __syncthreads();
    stageW(W2g, kb, wstage);
    __syncthreads();
    short8 afr[2];
#pragma unroll
    for (int rt=0;rt<2;++rt){
      int r = w*32 + rt*16 + l15;
      afr[rt] = *(const short8*)(hbuf + r*136 + kb + (lq<<3));
    }
#pragma unroll
    for (int nt=0;nt<8;++nt){
      short8 bfr = *(const short8*)(wstage + (nt*16 + l15)*40 + (lq<<3));
      acc2[0][nt] = MFMA16(afr[0], bfr, acc2[0][nt]);
      acc2[1][nt] = MFMA16(afr[1], bfr, acc2[1][nt]);
    }
  }
  __syncthreads();          // all H1 reads done before overwrite
#pragma unroll
  for (int rt=0;rt<2;++rt)
#pragma unroll
    for (int nt=0;nt<8;++nt){
      int col = nt*16 + l15;
      int r0 = w*32 + rt*16 + (lq<<2);
      float bv = biasb[128+col];
#pragma unroll
      for (int j=0;j<4;++j)
        hbuf[(r0+j)*136 + col] = f2bf(fmaxf(acc2[rt][nt][j] + bv, 0.f));
    }
  __syncthreads();

  // ---- GEMM3: H2(128x128) @ W3[g] ----
  f32x4 acc3[2][8];
#pragma unroll
  for (int rt=0;rt<2;++rt)
#pragma unroll
    for (int nt=0;nt<8;++nt) acc3[rt][nt] = zf;

  const float* W3g = W3 + (size_t)g*DD*DD;
  for (int kb = 0; kb < DD; kb += 32){
    __syncthreads();
    stageW(W3g, kb, wstage);
    __syncthreads();
    short8 afr[2];
#pragma unroll
    for (int rt=0;rt<2;++rt){
      int r = w*32 + rt*16 + l15;
      afr[rt] = *(const short8*)(hbuf + r*136 + kb + (lq<<3));
    }
#pragma unroll
    for (int nt=0;nt<8;++nt){
      short8 bfr = *(const short8*)(wstage + (nt*16 + l15)*40 + (lq<<3));
      acc3[0][nt] = MFMA16(afr[0], bfr, acc3[0][nt]);
      acc3[1][nt] = MFMA16(afr[1], bfr, acc3[1][nt]);
    }
  }
  __syncthreads();          // all H2 reads done
  // msg = pair-sum over F + 2*b3 -> hbuf rows 0..63 (bf16)
#pragma unroll
  for (int nt=0;nt<8;++nt){
    int col = nt*16 + l15;
    float b3v = 2.f*biasb[256+col];
#pragma unroll
    for (int rt=0;rt<2;++rt){
      int nit0 = w*16 + rt*8 + (lq<<1);
      float m0 = acc3[rt][nt][0] + acc3[rt][nt][1] + b3v;
      float m1 = acc3[rt][nt][2] + acc3[rt][nt][3] + b3v;
      hbuf[nit0*136 + col]     = f2bf(m0);
      hbuf[(nit0+1)*136 + col] = f2bf(m1);
    }
  }
  __syncthreads();

  // ---- GRU: gi = msg(64x128) @ Wi[g](128x384); h == 0 so gh == bh ----
  const int lo = lvl*MM;
  const float* Wig = Wi + (size_t)g*DD*3*DD;
  for (int dt = 0; dt < 8; ++dt){
    __syncthreads();
    {
      int c = tid & 15, k0 = tid >> 4;   // k0 in [0,16)
#pragma unroll
      for (int p = 0; p < 3; ++p)
#pragma unroll
        for (int s2 = 0; s2 < 8; ++s2){
          int k = k0 + (s2<<4);
          wstage[(p*16 + c)*136 + k] = f2bf(Wig[(size_t)k*384 + p*DD + dt*16 + c]);
        }
    }
    __syncthreads();
    f32x4 aR = zf, aZ = zf, aN = zf;
    for (int kb = 0; kb < DD; kb += 32){
      short8 afr = *(const short8*)(hbuf + (w*16 + l15)*136 + kb + (lq<<3));
      short8 bR = *(const short8*)(wstage + (( 0 + l15)*136 + kb + (lq<<3)));
      short8 bZ = *(const short8*)(wstage + ((16 + l15)*136 + kb + (lq<<3)));
      short8 bN = *(const short8*)(wstage + ((32 + l15)*136 + kb + (lq<<3)));
      aR = MFMA16(afr, bR, aR);
      aZ = MFMA16(afr, bZ, aZ);
      aN = MFMA16(afr, bN, aN);
    }
    int dcol = dt*16 + l15;
    float biR = biasb[384+dcol], biZ = biasb[384+DD+dcol], biN = biasb[384+2*DD+dcol];
    float bhR = biasb[768+dcol], bhZ = biasb[768+DD+dcol], bhN = biasb[768+2*DD+dcol];
#pragma unroll
    for (int j = 0; j < 4; ++j){
      int nit = w*16 + (lq<<2) + j;
      int m = nodebuf[nit];
      if (m < 0) continue;
      float xr = aR[j] + biR + bhR;
      float xz = aZ[j] + biZ + bhZ;
      float r_ = 1.f/(1.f + __expf(-xr));
      float z_ = 1.f/(1.f + __expf(-xz));
      float xn = aN[j] + biN + r_*bhN;
      float n_ = 2.f/(1.f + __expf(-2.f*xn)) - 1.f;
      hfg[(size_t)(lo + m)*DD + dcol] = (1.f - z_)*n_;
    }
  }
}

extern "C" void kernel_launch(void* const* d_in, const int* in_sizes, int n_in,
                              void* d_out, int out_size, void* d_ws, size_t ws_size,
                              hipStream_t stream)
{
  const float* s    = (const float*)d_in[0];
  const float* t    = (const float*)d_in[1];
  const int*   gate = (const int*)d_in[2];
  const int*   fanin= (const int*)d_in[3];
  const float* hs_W = (const float*)d_in[4];
  const float* hs_b = (const float*)d_in[5];
  const float* W1   = (const float*)d_in[6];
  const float* b1   = (const float*)d_in[7];
  const float* W2   = (const float*)d_in[8];
  const float* b2   = (const float*)d_in[9];
  const float* W3   = (const float*)d_in[10];
  const float* b3   = (const float*)d_in[11];
  const float* Wi   = (const float*)d_in[12];
  // d_in[13] = gru_Wh: unused (hidden state is exactly zero)
  const float* bi   = (const float*)d_in[14];
  const float* bh   = (const float*)d_in[15];

  float* hs = (float*)d_out;
  float* hf = hs + (size_t)NN*DD;

  int* cnt    = (int*)d_ws;        // [7][5]
  int* cur    = cnt + 35;          // [7][5]
  int* off    = cnt + 70;          // [7][5]
  int* pendv  = cnt + 105;         // [7][5]
  int* sorted = cnt + 256;         // [7][SORT_STRIDE]

  hipMemsetAsync(cnt, 0, 70*sizeof(int), stream);
  hipMemsetAsync(sorted, 0xFF, (size_t)(LL-1)*SORT_STRIDE*sizeof(int), stream);
  hipMemsetAsync(hf, 0, (size_t)MM*DD*sizeof(float), stream);   // level-0 hf slice stays zero

  count_kernel<<<896, 256, 0, stream>>>(gate, cnt);
  offs_kernel<<<1, 64, 0, stream>>>(cnt, off, pendv);
  scatter_kernel<<<896, 256, 0, stream>>>(gate, off, cur, sorted);
  hs_kernel<<<NN/256, 256, 0, stream>>>(s, t, hs_W, hs_b, hs);
  for (int lvl = 1; lvl < LL; ++lvl){
    level_kernel<<<SORT_STRIDE/64, 256, 0, stream>>>(lvl, hs, hf, fanin,
        W1, b1, W2, b2, W3, b3, Wi, bi, bh, off, pendv, sorted);
  }
}

// Round 2
// 900.262 us; speedup vs baseline: 2.8908x; 2.8908x over previous
//
#include <hip/hip_runtime.h>
#include <hip/hip_bf16.h>

#define DD 128
#define LL 8
#define MM 32768
#define NN (LL*MM)
#define GG 5
#define FF 2
#define SORT_STRIDE 33408   // 32768 + 5*128 headroom

typedef __attribute__((ext_vector_type(8))) short short8;
typedef __attribute__((ext_vector_type(4))) float f32x4;

#define MFMA16(a,b,c) __builtin_amdgcn_mfma_f32_16x16x32_bf16((a),(b),(c),0,0,0)

__device__ __forceinline__ short f2bf(float x){
  __hip_bfloat16 h = __float2bfloat16(x);
  return *reinterpret_cast<short*>(&h);
}

__device__ __forceinline__ short8 pack8(float4 a, float4 b){
  short8 r;
  r[0]=f2bf(a.x); r[1]=f2bf(a.y); r[2]=f2bf(a.z); r[3]=f2bf(a.w);
  r[4]=f2bf(b.x); r[5]=f2bf(b.y); r[6]=f2bf(b.z); r[7]=f2bf(b.w);
  return r;
}

// Stage rows [kb,kb+32) of a row-major (*,128) f32 matrix into LDS transposed:
// wt[col*40 + k], k in [0,32). Stride 40 (+8 pad) -> 2-way (free) bank pattern
// on the b128 fragment reads.
__device__ __forceinline__ void stageW(const float* __restrict__ Wp, int kb, short* wt){
  const int t = threadIdx.x;
  const int cb = (t & 31) << 2;
  const int kr = t >> 5;
#pragma unroll
  for (int s2 = 0; s2 < 4; ++s2){
    const int k = kr + (s2 << 3);
    float4 v = *(const float4*)(Wp + (size_t)(kb + k)*DD + cb);
    wt[(cb+0)*40 + k] = f2bf(v.x);
    wt[(cb+1)*40 + k] = f2bf(v.y);
    wt[(cb+2)*40 + k] = f2bf(v.z);
    wt[(cb+3)*40 + k] = f2bf(v.w);
  }
}

// ---------------- bucket sort by gate, per level ----------------
// 128 blocks per level (blockIdx.x>>7 = level index). LDS histogram first,
// then 5 global atomics per block (was: 256 -> atomic contention, ~900us).
__global__ void count_kernel(const int* __restrict__ gate, int* __restrict__ cnt){
  __shared__ int lc[GG];
  const int li = blockIdx.x >> 7;
  const int m  = ((blockIdx.x & 127) << 8) + threadIdx.x;
  if (threadIdx.x < GG) lc[threadIdx.x] = 0;
  __syncthreads();
  int g = gate[(li+1)*MM + m];
  atomicAdd(&lc[g], 1);
  __syncthreads();
  if (threadIdx.x < GG && lc[threadIdx.x] > 0)
    atomicAdd(&cnt[li*GG + threadIdx.x], lc[threadIdx.x]);
}

__global__ void offs_kernel(const int* __restrict__ cnt, int* __restrict__ off, int* __restrict__ pend){
  int l = threadIdx.x;
  if (l < LL-1){
    int o = 0;
    for (int g = 0; g < GG; ++g){
      off[l*GG+g] = o;
      int c = cnt[l*GG+g];
      pend[l*GG+g] = o + c;                 // valid region end
      o += ((c + 127) >> 7) << 7;           // pad each bucket to 128
    }
  }
}

__global__ void scatter_kernel(const int* __restrict__ gate, const int* __restrict__ off,
                               int* __restrict__ cur, int* __restrict__ sorted){
  __shared__ int lc[GG];
  __shared__ int base[GG];
  const int li = blockIdx.x >> 7;
  const int m  = ((blockIdx.x & 127) << 8) + threadIdx.x;
  if (threadIdx.x < GG) lc[threadIdx.x] = 0;
  __syncthreads();
  int g = gate[(li+1)*MM + m];
  int p = atomicAdd(&lc[g], 1);           // local rank within block
  __syncthreads();
  if (threadIdx.x < GG)
    base[threadIdx.x] = atomicAdd(&cur[li*GG + threadIdx.x], lc[threadIdx.x]);
  __syncthreads();
  sorted[li*SORT_STRIDE + off[li*GG+g] + base[g] + p] = m;
}

// ---------------- hs = [s|t] @ hs_W + hs_b ----------------
__global__ __launch_bounds__(256) void hs_kernel(
    const float* __restrict__ s, const float* __restrict__ t,
    const float* __restrict__ W, const float* __restrict__ b,
    float* __restrict__ hs)
{
  __shared__ __align__(16) short wt[128*40];
  __shared__ float bias[128];
  const int tid = threadIdx.x, lane = tid & 63, w = tid >> 6;
  const int l15 = lane & 15, lq = lane >> 4;
  if (tid < 128) bias[tid] = b[tid];
  const int row0 = blockIdx.x*256 + w*64;

  f32x4 zf = {0.f,0.f,0.f,0.f};
  f32x4 acc[4][8];
#pragma unroll
  for (int rt=0;rt<4;++rt)
#pragma unroll
    for (int nt=0;nt<8;++nt) acc[rt][nt] = zf;

  for (int kb = 0; kb < 2*DD; kb += 32){
    __syncthreads();
    stageW(W, kb, wt);
    __syncthreads();
    const float* base = (kb < DD) ? s : t;
    const int koff = kb & (DD-1);
    short8 afr[4];
#pragma unroll
    for (int rt=0;rt<4;++rt){
      int gr = row0 + rt*16 + l15;
      const float* p = base + (size_t)gr*DD + koff + (lq<<3);
      afr[rt] = pack8(*(const float4*)p, *(const float4*)(p+4));
    }
#pragma unroll
    for (int nt=0;nt<8;++nt){
      short8 bfr = *(const short8*)(wt + (nt*16 + l15)*40 + (lq<<3));
#pragma unroll
      for (int rt=0;rt<4;++rt)
        acc[rt][nt] = MFMA16(afr[rt], bfr, acc[rt][nt]);
    }
  }
#pragma unroll
  for (int rt=0;rt<4;++rt)
#pragma unroll
    for (int nt=0;nt<8;++nt){
      int col = nt*16 + l15;
      int r0 = row0 + rt*16 + (lq<<2);
      float bv = bias[col];
#pragma unroll
      for (int j=0;j<4;++j)
        hs[(size_t)(r0+j)*DD + col] = acc[rt][nt][j] + bv;
    }
}

// ---------------- fused per-level kernel ----------------
// Block: 64 nodes of one gate bucket (128 (node,fanin) rows).
// GEMM1 (256->128, gathered A) -> relu -> GEMM2 (128->128) -> relu ->
// GEMM3 (128->128) -> pair-sum over F -> msg -> GRU GEMM (128->3*128) ->
// sigmoid/tanh epilogue -> hf scatter.
__global__ __launch_bounds__(256) void level_kernel(
    int lvl, const float* __restrict__ hsg, float* __restrict__ hfg,
    const int* __restrict__ fanin,
    const float* __restrict__ W1, const float* __restrict__ b1,
    const float* __restrict__ W2, const float* __restrict__ b2,
    const float* __restrict__ W3, const float* __restrict__ b3,
    const float* __restrict__ Wi, const float* __restrict__ bi,
    const float* __restrict__ bh,
    const int* __restrict__ off, const int* __restrict__ pend,
    const int* __restrict__ sorted)
{
  __shared__ __align__(16) short hbuf[128*136];
  __shared__ __align__(16) short wstage[6528];   // max(128*40, 48*136)
  __shared__ float biasb[128*3 + 384*2];         // b1,b2,b3,bi,bh
  __shared__ int nodebuf[64];
  __shared__ int srcbuf[128];
  __shared__ int ginfo[1];

  const int tid = threadIdx.x;
  const int lane = tid & 63;
  const int w = tid >> 6;
  const int li = lvl - 1;
  const int pos0 = blockIdx.x * 64;
  const int l15 = lane & 15, lq = lane >> 4;

  if (tid == 0){
    int g = -1;
    for (int q = 0; q < GG; ++q)
      if (pos0 >= off[li*GG+q] && pos0 < pend[li*GG+q]) { g = q; break; }
    ginfo[0] = g;
  }
  __syncthreads();
  const int g = ginfo[0];
  if (g < 0) return;                 // uniform across block

  if (tid < 64) nodebuf[tid] = sorted[li*SORT_STRIDE + pos0 + tid];
  if (tid < 128){
    biasb[tid]     = b1[g*DD + tid];
    biasb[128+tid] = b2[g*DD + tid];
    biasb[256+tid] = b3[g*DD + tid];
  }
  for (int i = tid; i < 384; i += 256){
    biasb[384+i] = bi[g*384 + i];
    biasb[768+i] = bh[g*384 + i];
  }
  __syncthreads();
  if (tid < 128){
    int m = nodebuf[tid>>1];
    int sv = 0;
    if (m >= 0) sv = li*MM + fanin[((size_t)li*MM + m)*FF + (tid & 1)];
    srcbuf[tid] = sv;
  }

  f32x4 zf = {0.f,0.f,0.f,0.f};

  // ---- GEMM1: X(128x256) @ W1[g](256x128) ----
  f32x4 acc[2][8];
#pragma unroll
  for (int rt=0;rt<2;++rt)
#pragma unroll
    for (int nt=0;nt<8;++nt) acc[rt][nt] = zf;

  const float* W1g = W1 + (size_t)g*2*DD*DD;
  for (int kb = 0; kb < 2*DD; kb += 32){
    __syncthreads();
    stageW(W1g, kb, wstage);
    __syncthreads();
    const float* base = (kb < DD) ? hsg : hfg;
    const int koff = kb & (DD-1);
    short8 afr[2];
#pragma unroll
    for (int rt=0;rt<2;++rt){
      int r = w*32 + rt*16 + l15;
      int src = srcbuf[r];
      const float* p = base + (size_t)src*DD + koff + (lq<<3);
      afr[rt] = pack8(*(const float4*)p, *(const float4*)(p+4));
    }
#pragma unroll
    for (int nt=0;nt<8;++nt){
      short8 bfr = *(const short8*)(wstage + (nt*16 + l15)*40 + (lq<<3));
      acc[0][nt] = MFMA16(afr[0], bfr, acc[0][nt]);
      acc[1][nt] = MFMA16(afr[1], bfr, acc[1][nt]);
    }
  }
#pragma unroll
  for (int rt=0;rt<2;++rt)
#pragma unroll
    for (int nt=0;nt<8;++nt){
      int col = nt*16 + l15;
      int r0 = w*32 + rt*16 + (lq<<2);
      float bv = biasb[col];
#pragma unroll
      for (int j=0;j<4;++j)
        hbuf[(r0+j)*136 + col] = f2bf(fmaxf(acc[rt][nt][j] + bv, 0.f));
    }
  __syncthreads();

  // ---- GEMM2: H1(128x128) @ W2[g] ----
  f32x4 acc2[2][8];
#pragma unroll
  for (int rt=0;rt<2;++rt)
#pragma unroll
    for (int nt=0;nt<8;++nt) acc2[rt][nt] = zf;

  const float* W2g = W2 + (size_t)g*DD*DD;
  for (int kb = 0; kb < DD; kb += 32){
    __syncthreads();
    stageW(W2g, kb, wstage);
    __syncthreads();
    short8 afr[2];
#pragma unroll
    for (int rt=0;rt<2;++rt){
      int r = w*32 + rt*16 + l15;
      afr[rt] = *(const short8*)(hbuf + r*136 + kb + (lq<<3));
    }
#pragma unroll
    for (int nt=0;nt<8;++nt){
      short8 bfr = *(const short8*)(wstage + (nt*16 + l15)*40 + (lq<<3));
      acc2[0][nt] = MFMA16(afr[0], bfr, acc2[0][nt]);
      acc2[1][nt] = MFMA16(afr[1], bfr, acc2[1][nt]);
    }
  }
  __syncthreads();          // all H1 reads done before overwrite
#pragma unroll
  for (int rt=0;rt<2;++rt)
#pragma unroll
    for (int nt=0;nt<8;++nt){
      int col = nt*16 + l15;
      int r0 = w*32 + rt*16 + (lq<<2);
      float bv = biasb[128+col];
#pragma unroll
      for (int j=0;j<4;++j)
        hbuf[(r0+j)*136 + col] = f2bf(fmaxf(acc2[rt][nt][j] + bv, 0.f));
    }
  __syncthreads();

  // ---- GEMM3: H2(128x128) @ W3[g] ----
  f32x4 acc3[2][8];
#pragma unroll
  for (int rt=0;rt<2;++rt)
#pragma unroll
    for (int nt=0;nt<8;++nt) acc3[rt][nt] = zf;

  const float* W3g = W3 + (size_t)g*DD*DD;
  for (int kb = 0; kb < DD; kb += 32){
    __syncthreads();
    stageW(W3g, kb, wstage);
    __syncthreads();
    short8 afr[2];
#pragma unroll
    for (int rt=0;rt<2;++rt){
      int r = w*32 + rt*16 + l15;
      afr[rt] = *(const short8*)(hbuf + r*136 + kb + (lq<<3));
    }
#pragma unroll
    for (int nt=0;nt<8;++nt){
      short8 bfr = *(const short8*)(wstage + (nt*16 + l15)*40 + (lq<<3));
      acc3[0][nt] = MFMA16(afr[0], bfr, acc3[0][nt]);
      acc3[1][nt] = MFMA16(afr[1], bfr, acc3[1][nt]);
    }
  }
  __syncthreads();          // all H2 reads done
  // msg = pair-sum over F + 2*b3 -> hbuf rows 0..63 (bf16)
#pragma unroll
  for (int nt=0;nt<8;++nt){
    int col = nt*16 + l15;
    float b3v = 2.f*biasb[256+col];
#pragma unroll
    for (int rt=0;rt<2;++rt){
      int nit0 = w*16 + rt*8 + (lq<<1);
      float m0 = acc3[rt][nt][0] + acc3[rt][nt][1] + b3v;
      float m1 = acc3[rt][nt][2] + acc3[rt][nt][3] + b3v;
      hbuf[nit0*136 + col]     = f2bf(m0);
      hbuf[(nit0+1)*136 + col] = f2bf(m1);
    }
  }
  __syncthreads();

  // ---- GRU: gi = msg(64x128) @ Wi[g](128x384); h == 0 so gh == bh ----
  const int lo = lvl*MM;
  const float* Wig = Wi + (size_t)g*DD*3*DD;
  for (int dt = 0; dt < 8; ++dt){
    __syncthreads();
    {
      int c = tid & 15, k0 = tid >> 4;   // k0 in [0,16)
#pragma unroll
      for (int p = 0; p < 3; ++p)
#pragma unroll
        for (int s2 = 0; s2 < 8; ++s2){
          int k = k0 + (s2<<4);
          wstage[(p*16 + c)*136 + k] = f2bf(Wig[(size_t)k*384 + p*DD + dt*16 + c]);
        }
    }
    __syncthreads();
    f32x4 aR = zf, aZ = zf, aN = zf;
    for (int kb = 0; kb < DD; kb += 32){
      short8 afr = *(const short8*)(hbuf + (w*16 + l15)*136 + kb + (lq<<3));
      short8 bR = *(const short8*)(wstage + (( 0 + l15)*136 + kb + (lq<<3)));
      short8 bZ = *(const short8*)(wstage + ((16 + l15)*136 + kb + (lq<<3)));
      short8 bN = *(const short8*)(wstage + ((32 + l15)*136 + kb + (lq<<3)));
      aR = MFMA16(afr, bR, aR);
      aZ = MFMA16(afr, bZ, aZ);
      aN = MFMA16(afr, bN, aN);
    }
    int dcol = dt*16 + l15;
    float biR = biasb[384+dcol], biZ = biasb[384+DD+dcol], biN = biasb[384+2*DD+dcol];
    float bhR = biasb[768+dcol], bhZ = biasb[768+DD+dcol], bhN = biasb[768+2*DD+dcol];
#pragma unroll
    for (int j = 0; j < 4; ++j){
      int nit = w*16 + (lq<<2) + j;
      int m = nodebuf[nit];
      if (m < 0) continue;
      float xr = aR[j] + biR + bhR;
      float xz = aZ[j] + biZ + bhZ;
      float r_ = 1.f/(1.f + __expf(-xr));
      float z_ = 1.f/(1.f + __expf(-xz));
      float xn = aN[j] + biN + r_*bhN;
      float n_ = 2.f/(1.f + __expf(-2.f*xn)) - 1.f;
      hfg[(size_t)(lo + m)*DD + dcol] = (1.f - z_)*n_;
    }
  }
}

extern "C" void kernel_launch(void* const* d_in, const int* in_sizes, int n_in,
                              void* d_out, int out_size, void* d_ws, size_t ws_size,
                              hipStream_t stream)
{
  const float* s    = (const float*)d_in[0];
  const float* t    = (const float*)d_in[1];
  const int*   gate = (const int*)d_in[2];
  const int*   fanin= (const int*)d_in[3];
  const float* hs_W = (const float*)d_in[4];
  const float* hs_b = (const float*)d_in[5];
  const float* W1   = (const float*)d_in[6];
  const float* b1   = (const float*)d_in[7];
  const float* W2   = (const float*)d_in[8];
  const float* b2   = (const float*)d_in[9];
  const float* W3   = (const float*)d_in[10];
  const float* b3   = (const float*)d_in[11];
  const float* Wi   = (const float*)d_in[12];
  // d_in[13] = gru_Wh: unused (hidden state is exactly zero)
  const float* bi   = (const float*)d_in[14];
  const float* bh   = (const float*)d_in[15];

  float* hs = (float*)d_out;
  float* hf = hs + (size_t)NN*DD;

  int* cnt    = (int*)d_ws;        // [7][5]
  int* cur    = cnt + 35;          // [7][5]
  int* off    = cnt + 70;          // [7][5]
  int* pendv  = cnt + 105;         // [7][5]
  int* sorted = cnt + 256;         // [7][SORT_STRIDE]

  hipMemsetAsync(cnt, 0, 70*sizeof(int), stream);
  hipMemsetAsync(sorted, 0xFF, (size_t)(LL-1)*SORT_STRIDE*sizeof(int), stream);
  hipMemsetAsync(hf, 0, (size_t)MM*DD*sizeof(float), stream);   // level-0 hf slice stays zero

  count_kernel<<<896, 256, 0, stream>>>(gate, cnt);
  offs_kernel<<<1, 64, 0, stream>>>(cnt, off, pendv);
  scatter_kernel<<<896, 256, 0, stream>>>(gate, off, cur, sorted);
  hs_kernel<<<NN/256, 256, 0, stream>>>(s, t, hs_W, hs_b, hs);
  for (int lvl = 1; lvl < LL; ++lvl){
    level_kernel<<<SORT_STRIDE/64, 256, 0, stream>>>(lvl, hs, hf, fanin,
        W1, b1, W2, b2, W3, b3, Wi, bi, bh, off, pendv, sorted);
  }
}